// Round 4
// baseline (385.557 us; speedup 1.0000x reference)
//
#include <hip/hip_runtime.h>

#define B_ 256
#define T_ 512
#define N_ 128

typedef float float2v __attribute__((ext_vector_type(2)));

// Barrier draining only LDS (lgkmcnt), not vmcnt: emission prefetches stay
// in flight across it (__syncthreads() would emit vmcnt(0) and serialize
// the global-load pipeline into every step).
__device__ __forceinline__ void barrier_lds() {
    asm volatile("s_waitcnt lgkmcnt(0)\n\ts_barrier" ::: "memory");
}

__device__ __forceinline__ float readlane_f(float v, int k) {
    return __int_as_float(__builtin_amdgcn_readlane(__float_as_int(v), k));
}

// One block (4 waves) per batch. Wave w owns contraction quarter
// i in [32w, 32w+32); every wave covers all 128 outputs (j=l in .x,
// j=64+l in .y). q broadcasts come straight from the replicated v0/v1
// registers via v_readlane (no bpermute, no LDS). Readlanes are chunked
// (8 at a time into SGPRs, then 8 pk_fma) to bury the VALU->SGPR->VALU
// hazard. Partials combine through LDS as float2 (1 ds_write_b64 +
// 3 ds_read_b64 per lane), double-buffered, ONE barrier per step.
// q is scaled-exp domain; every 4th step rescale by combined s_0
// (readlane, no reduction), log accumulated in Macc (block-uniform).
__global__ __launch_bounds__(256, 1) void crf_fused_kernel(
    const float* __restrict__ lp,      // [B,T,N]
    const float* __restrict__ trans,   // [N,N]
    const float* __restrict__ startt,  // [N]
    const float* __restrict__ endt,    // [N]
    const int*   __restrict__ target,  // [B,T]
    const int*   __restrict__ lengths, // [B]
    float*       __restrict__ out)     // [B]
{
    const int b   = blockIdx.x;
    const int tid = threadIdx.x;
    const int w   = tid >> 6;          // wave 0..3 = i-quarter
    const int l   = tid & 63;

    __shared__ float2v part[2][4][64]; // [parity][wave][lane] = {p_j=l, p_j=64+l}
    __shared__ float red[8];

    // epair[k] = {exp(trans[32w+k][l]), exp(trans[32w+k][64+l])}
    float2v epair[32];
    {
        const float* tq = trans + (w << 5) * N_;
        #pragma unroll
        for (int k = 0; k < 32; ++k) {
            epair[k].x = __expf(tq[k * N_ + l]);
            epair[k].y = __expf(tq[k * N_ + 64 + l]);
        }
    }

    const float* lpb = lp + (size_t)b * (T_ * N_);
    const int len = lengths[b];        // in [256, 512]

    // t = 0 alphas in exp domain (replicated in every wave)
    float v0 = __expf(startt[l]      + lpb[l]);
    float v1 = __expf(startt[64 + l] + lpb[64 + l]);

    const int base = (w & 1) << 5;     // lane offset of this wave's q slice

    float Macc = 0.f;

    // emission prefetch pipeline, distance 2 (len >= 256 so rows 1,2 valid)
    float cur0 = lpb[N_ + l],     cur1 = lpb[N_ + 64 + l];
    float nx0  = lpb[2 * N_ + l], nx1  = lpb[2 * N_ + 64 + l];

    for (int t = 1; t < len; ++t) {
        const int tp = min(t + 2, T_ - 1);          // clamped prefetch
        float nn0 = lpb[(size_t)tp * N_ + l];
        float nn1 = lpb[(size_t)tp * N_ + 64 + l];

        float eexp0 = __expf(cur0);                 // off critical chain
        float eexp1 = __expf(cur1);

        // wave w's q slice lives in v0 (w<2) or v1 (w>=2), lanes base..base+31
        float vsrc = (w < 2) ? v0 : v1;

        float2v acc = {0.f, 0.f};
        #pragma unroll
        for (int c = 0; c < 32; c += 8) {
            float qs[8];
            #pragma unroll
            for (int r = 0; r < 8; ++r)
                qs[r] = readlane_f(vsrc, base + c + r);
            #pragma unroll
            for (int r = 0; r < 8; ++r) {
                float2v qv = {qs[r], qs[r]};
                acc = __builtin_elementwise_fma(qv, epair[c + r], acc);
            }
        }

        const int pb = t & 1;
        part[pb][w][l] = acc;          // ds_write_b64
        barrier_lds();                 // ONE barrier per step

        float2v s = acc;
        s += part[pb][(w + 1) & 3][l]; // 3x ds_read_b64
        s += part[pb][(w + 2) & 3][l];
        s += part[pb][(w + 3) & 3][l];

        if ((t & 3) == 0) {            // deferred rescale (block-uniform)
            float sc  = readlane_f(s.x, 0);
            float isc = __builtin_amdgcn_rcpf(sc);
            s.x *= isc; s.y *= isc;
            Macc += __logf(sc);
        }

        v0 = s.x * eexp0;              // next q, replicated in all waves
        v1 = s.y * eexp1;

        cur0 = nx0; cur1 = nx1; nx0 = nn0; nx1 = nn1;
    }

    // ---- log Z from wave 0's replica ----
    if (w == 0) {
        float f = v0 * __expf(endt[l]) + v1 * __expf(endt[64 + l]);
        #pragma unroll
        for (int off = 32; off > 0; off >>= 1) f += __shfl_xor(f, off);
        if (l == 0) red[0] = Macc + __logf(f);
    }

    // ---- path score (gathers), all 256 threads ----
    const int* tg = target + b * T_;
    float acc = 0.f;
    for (int t = tid; t < len; t += 256) {
        int c = tg[t];
        acc += lpb[t * N_ + c];
        if (t + 1 < len) acc += trans[c * N_ + tg[t + 1]];
    }
    #pragma unroll
    for (int off = 32; off > 0; off >>= 1) acc += __shfl_xor(acc, off);
    if (l == 0) red[4 + w] = acc;
    __syncthreads();

    if (tid == 0) {
        float sc = red[4] + red[5] + red[6] + red[7];
        out[b] = sc + startt[tg[0]] + endt[tg[len - 1]] - red[0];
    }
}

extern "C" void kernel_launch(void* const* d_in, const int* in_sizes, int n_in,
                              void* d_out, int out_size, void* d_ws, size_t ws_size,
                              hipStream_t stream) {
    const float* lp     = (const float*)d_in[0];
    const float* trans  = (const float*)d_in[1];
    const float* st     = (const float*)d_in[2];
    const float* en     = (const float*)d_in[3];
    const int*   target = (const int*)d_in[4];
    const int*   lens   = (const int*)d_in[5];
    float* out = (float*)d_out;

    crf_fused_kernel<<<B_, 256, 0, stream>>>(lp, trans, st, en, target, lens, out);
}

// Round 6
// 286.784 us; speedup vs baseline: 1.3444x; 1.3444x over previous
//
#include <hip/hip_runtime.h>

#define B_ 256
#define T_ 512
#define N_ 128

typedef _Float16 half2v  __attribute__((ext_vector_type(2)));  // fdot2 operand type
typedef float    float2v __attribute__((ext_vector_type(2)));

// pack two f32 -> f16x2, bit_cast to the fdot2 operand type
__device__ __forceinline__ half2v pk16(float a, float b) {
    return __builtin_bit_cast(half2v, __builtin_amdgcn_cvt_pkrtz(a, b));
}

// Barrier draining only LDS (lgkmcnt), not vmcnt: emission prefetches stay
// in flight across it (__syncthreads() emits vmcnt(0) and would serialize
// the global-load pipeline into every step).
__device__ __forceinline__ void barrier_lds() {
    asm volatile("s_waitcnt lgkmcnt(0)\n\ts_barrier" ::: "memory");
}

__device__ __forceinline__ int readlane_i(int v, int k) {
    return __builtin_amdgcn_readlane(v, k);
}
__device__ __forceinline__ float readlane_f(float v, int k) {
    return __int_as_float(__builtin_amdgcn_readlane(__float_as_int(v), k));
}

// One block (4 waves) per batch. Lane l owns output states j0=2l, j1=2l+1.
// Wave w owns contraction quarter i in [32w, 32w+32) = 16 i-pairs.
// q lives replicated in registers as f32 (v0,v1) and as packed f16 pairs
// (qp, lane m holds {q_2m, q_2m+1}); broadcasts via v_readlane -> SGPR,
// consumed by v_dot2_f32_f16 (16 readlane + 32 fdot2 per step per lane).
// Cross-wave combine: partials in lane-major LDS (part[pb][l][w]) -> one
// ds_write_b64 + two ds_read_b128; ONE lgkm-only barrier per step.
// q is rescaled EVERY step by its j=0 element (readlane, no reduction) to
// keep the f16 pack in range; logs of scales accumulate in Macc.
__global__ __launch_bounds__(256, 1) void crf_fused_kernel(
    const float* __restrict__ lp,      // [B,T,N]
    const float* __restrict__ trans,   // [N,N]
    const float* __restrict__ startt,  // [N]
    const float* __restrict__ endt,    // [N]
    const int*   __restrict__ target,  // [B,T]
    const int*   __restrict__ lengths, // [B]
    float*       __restrict__ out)     // [B]
{
    const int b   = blockIdx.x;
    const int tid = threadIdx.x;
    const int w   = tid >> 6;          // wave 0..3 = i-quarter
    const int l   = tid & 63;
    const int j0  = 2 * l;             // this lane's two output states

    __shared__ __align__(32) float2v part[2][64][4];  // [parity][lane][wave]
    __shared__ float red[8];

    // f16 transition pairs: ej0[m] = {e(i0,j0), e(i0+1,j0)}, ej1 for j0+1,
    // where i0 = 32w + 2m. Loads are coalesced float2 (64 lanes x 8B).
    half2v ej0[16], ej1[16];
    #pragma unroll
    for (int m = 0; m < 16; ++m) {
        const int i0 = (w << 5) + 2 * m;
        float2v te0 = *(const float2v*)(trans + i0 * N_ + j0);
        float2v te1 = *(const float2v*)(trans + (i0 + 1) * N_ + j0);
        ej0[m] = pk16(__expf(te0.x), __expf(te1.x));
        ej1[m] = pk16(__expf(te0.y), __expf(te1.y));
    }

    const float* lpb = lp + (size_t)b * (T_ * N_);
    const int len = lengths[b];        // in [256, 512]

    // t = 0 init (replicated in every wave), rescaled by element j=0
    float v0, v1, Macc;
    {
        float2v st2 = *(const float2v*)(startt + j0);
        float2v e0r = *(const float2v*)(lpb + j0);
        float a = __expf(st2.x + e0r.x);
        float c = __expf(st2.y + e0r.y);
        float sc  = readlane_f(a, 0);
        float isc = __builtin_amdgcn_rcpf(sc);
        v0 = a * isc; v1 = c * isc;
        Macc = __logf(sc);
    }
    half2v qp = pk16(v0, v1);

    // emission prefetch pipeline, distance 2 (len >= 256: rows 1,2 valid)
    float2v cur = *(const float2v*)(lpb + N_ + j0);
    float2v nx  = *(const float2v*)(lpb + 2 * N_ + j0);

    for (int t = 1; t < len; ++t) {
        const int tp = (t + 2 < T_) ? t + 2 : T_ - 1;   // clamped, in-bounds
        float2v nn = *(const float2v*)(lpb + (size_t)tp * N_ + j0);

        float eexp0 = __expf(cur.x);   // hoisted off the post-combine chain
        float eexp1 = __expf(cur.y);

        // quarter contraction: 16 readlane (chunked 4) + 32 fdot2
        const int qpi = __builtin_bit_cast(int, qp);
        float a0 = 0.f, a1 = 0.f;
        #pragma unroll
        for (int c = 0; c < 16; c += 4) {
            int s0 = readlane_i(qpi, (w << 4) + c + 0);
            int s1 = readlane_i(qpi, (w << 4) + c + 1);
            int s2 = readlane_i(qpi, (w << 4) + c + 2);
            int s3 = readlane_i(qpi, (w << 4) + c + 3);
            half2v h0 = __builtin_bit_cast(half2v, s0);
            half2v h1 = __builtin_bit_cast(half2v, s1);
            half2v h2 = __builtin_bit_cast(half2v, s2);
            half2v h3 = __builtin_bit_cast(half2v, s3);
            a0 = __builtin_amdgcn_fdot2(h0, ej0[c + 0], a0, false);
            a1 = __builtin_amdgcn_fdot2(h0, ej1[c + 0], a1, false);
            a0 = __builtin_amdgcn_fdot2(h1, ej0[c + 1], a0, false);
            a1 = __builtin_amdgcn_fdot2(h1, ej1[c + 1], a1, false);
            a0 = __builtin_amdgcn_fdot2(h2, ej0[c + 2], a0, false);
            a1 = __builtin_amdgcn_fdot2(h2, ej1[c + 2], a1, false);
            a0 = __builtin_amdgcn_fdot2(h3, ej0[c + 3], a0, false);
            a1 = __builtin_amdgcn_fdot2(h3, ej1[c + 3], a1, false);
        }

        const int pb = t & 1;
        part[pb][l][w] = (float2v){a0, a1};   // ds_write_b64
        barrier_lds();                         // ONE barrier per step

        // combine all 4 quarters, fixed order (bit-identical across waves):
        // two ds_read_b128, 32B lane stride (~2-way aliasing: free)
        const float4* pp = (const float4*)(&part[pb][l][0]);
        float4 xa = pp[0];                     // waves 0,1
        float4 xb = pp[1];                     // waves 2,3
        float sx = (xa.x + xa.z) + (xb.x + xb.z);
        float sy = (xa.y + xa.w) + (xb.y + xb.w);

        float nv0 = sx * eexp0;
        float nv1 = sy * eexp1;

        // per-step rescale by element j=0 (keeps f16 pack in range)
        float sc  = readlane_f(nv0, 0);
        float isc = __builtin_amdgcn_rcpf(sc);
        v0 = nv0 * isc;
        v1 = nv1 * isc;
        qp = pk16(v0, v1);
        Macc += __logf(sc);                    // off the critical chain

        cur = nx; nx = nn;
    }

    // ---- log Z from wave 0's replica ----
    if (w == 0) {
        float2v en2 = *(const float2v*)(endt + j0);
        float f = v0 * __expf(en2.x) + v1 * __expf(en2.y);
        #pragma unroll
        for (int off = 32; off > 0; off >>= 1) f += __shfl_xor(f, off);
        if (l == 0) red[0] = Macc + __logf(f);
    }

    // ---- path score (gathers), all 256 threads ----
    const int* tg = target + b * T_;
    float acc = 0.f;
    for (int t = tid; t < len; t += 256) {
        int c = tg[t];
        acc += lpb[t * N_ + c];
        if (t + 1 < len) acc += trans[c * N_ + tg[t + 1]];
    }
    #pragma unroll
    for (int off = 32; off > 0; off >>= 1) acc += __shfl_xor(acc, off);
    if (l == 0) red[4 + w] = acc;
    __syncthreads();

    if (tid == 0) {
        float sc = red[4] + red[5] + red[6] + red[7];
        out[b] = sc + startt[tg[0]] + endt[tg[len - 1]] - red[0];
    }
}

extern "C" void kernel_launch(void* const* d_in, const int* in_sizes, int n_in,
                              void* d_out, int out_size, void* d_ws, size_t ws_size,
                              hipStream_t stream) {
    const float* lp     = (const float*)d_in[0];
    const float* trans  = (const float*)d_in[1];
    const float* st     = (const float*)d_in[2];
    const float* en     = (const float*)d_in[3];
    const int*   target = (const int*)d_in[4];
    const int*   lens   = (const int*)d_in[5];
    float* out = (float*)d_out;

    crf_fused_kernel<<<B_, 256, 0, stream>>>(lp, trans, st, en, target, lens, out);
}